// Round 6
// baseline (298.288 us; speedup 1.0000x reference)
//
#include <hip/hip_runtime.h>
#include <hip/hip_bf16.h>

typedef __hip_bfloat16 bf16;

__device__ __forceinline__ float ldT(const bf16* p){ return __bfloat162float(*p); }
__device__ __forceinline__ float ldT(const float* p){ return *p; }

// load 2 consecutive elements (r,i pair) as float2
__device__ __forceinline__ float2 ld2T(const bf16* p){
    unsigned v = *(const unsigned*)p;          // [hi | lo] little-endian
    float2 r;
    r.x = __uint_as_float(v << 16);            // low bf16 -> f32 (exact)
    r.y = __uint_as_float(v & 0xFFFF0000u);    // high bf16 -> f32
    return r;
}
__device__ __forceinline__ float2 ld2T(const float* p){ return *(const float2*)p; }

__device__ __forceinline__ int refl(int i, int n){
    if (i < 0) return -1 - i;
    if (i >= n) return 2*n - 1 - i;
    return i;
}

__device__ __forceinline__ void store4(bf16* out, size_t idx,
                                       float o0, float o1, float o2, float o3){
    union { ushort4 u4; bf16 h[4]; } pk;
    pk.h[0] = __float2bfloat16(o0); pk.h[1] = __float2bfloat16(o1);
    pk.h[2] = __float2bfloat16(o2); pk.h[3] = __float2bfloat16(o3);
    *(ushort4*)(out + idx) = pk.u4;
}
__device__ __forceinline__ void store4(float* out, size_t idx,
                                       float o0, float o1, float o2, float o3){
    float4 st; st.x=o0; st.y=o1; st.z=o2; st.w=o3;
    *(float4*)(out + idx) = st;
}

// Write one 2x2 c2q cell. fr/fc = reflection parity flips for row/col.
__device__ __forceinline__ void wcell(float* B, int stride, int r0, int c0,
                                      int fr, int fc, float2 P, float2 Q){
    const float s = 0.70710678118654752f;
    float v00=(P.x+Q.x)*s, v01=(P.y+Q.y)*s, v10=(P.y-Q.y)*s, v11=(Q.x-P.x)*s;
    float t0 = fr ? v10 : v00, t1 = fr ? v11 : v01;   // row r0  : pu = fr
    float u0 = fr ? v00 : v10, u1 = fr ? v01 : v11;   // row r0+1: pu = 1^fr
    float2 w0 = fc ? make_float2(t1, t0) : make_float2(t0, t1);
    float2 w1 = fc ? make_float2(u1, u0) : make_float2(u0, u1);
    *(float2*)(B + r0*stride + c0)     = w0;
    *(float2*)(B + (r0+1)*stride + c0) = w1;
}

// Generate the symmetric-extended band tiles (LH,HL,HH) cell-wise.
template<typename T, int NC, int STRIDE>
__device__ __forceinline__ void band_cells(const T* yh, int b, int hs,
    int cor, int coc, float* LH, float* HL, float* HH, int tid){
    const size_t sstr = (size_t)hs * hs;
    const size_t ybase = (size_t)b * 6 * sstr;
    for (int idx = tid; idx < NC*NC; idx += 256){
        int i = idx / NC, j = idx % NC;
        int cr = cor + i; int fr = (cr < 0) | (cr >= hs); if (fr) cr = refl(cr, hs);
        int cc = coc + j; int fc = (cc < 0) | (cc >= hs); if (fc) cc = refl(cc, hs);
        size_t base = ybase + (size_t)cr*hs + cc;
        float2 a0 = ld2T(yh + 2*base);
        float2 a1 = ld2T(yh + 2*(base +   sstr));
        float2 a2 = ld2T(yh + 2*(base + 2*sstr));
        float2 a3 = ld2T(yh + 2*(base + 3*sstr));
        float2 a4 = ld2T(yh + 2*(base + 4*sstr));
        float2 a5 = ld2T(yh + 2*(base + 5*sstr));
        wcell(LH, STRIDE, 2*i, 2*j, fr, fc, a0, a5);
        wcell(HL, STRIDE, 2*i, 2*j, fr, fc, a2, a3);
        wcell(HH, STRIDE, 2*i, 2*j, fr, fc, a1, a4);
    }
}

// Per-line setup for the 10-tap quarter-shift synthesis (verified tap algebra):
//   q=0: hz=A[1+2k]  hb=-A[8-2k] | q=1: hz=A[8-2k]  hb= A[1+2k]
//   q=2: hz=A[2k]    hb= A[9-2k] | q=3: hz=A[9-2k]  hb=-A[2k]
// Computed ONCE per thread (statically-indexed register taps).
__device__ __forceinline__ void line_setup(const float (&A)[10], int G, int off,
                                           int& zb, int& bb, float (&hz)[5], float (&hb)[5]){
    int t = G >> 2, q = G & 3;
    bool q1 = q >= 2; int qa = q & 1;
    zb = 2*t - 4 + qa - off;
    bb = 2*t - 3 - qa - off;
    #pragma unroll
    for (int k = 0; k < 5; ++k){
        hz[k] = q1 ? (qa ? A[9-2*k] : A[2*k]) : (qa ? A[8-2*k] : A[1+2*k]);
        hb[k] = q1 ? (qa ? -A[2*k] : A[9-2*k]) : (qa ? A[1+2*k] : -A[8-2*k]);
    }
}

// LDS layout (bytes), stage-lifetime aliased; peak 31216 (unchanged from round 4)
#define FUSED_SMEM 31216

template<typename T>
__device__ void dtbody(char* smem, const T* yl, const T* yh0, const T* yh1, const T* yh2,
                       const T* g0a_, const T* g0o_, const T* g1o_, T* out)
{
    const int b  = blockIdx.z;
    const int R0 = blockIdx.y * 32, C0 = blockIdx.x * 32;
    const int tid = threadIdx.x;

    float (*ylT)[26]  = (float(*)[26])(smem);
    float (*b2LH)[26] = (float(*)[26])(smem + 2496);
    float (*b2HL)[26] = (float(*)[26])(smem + 4992);
    float (*b2HH)[26] = (float(*)[26])(smem + 7488);
    float (*Y1a)[25]  = (float(*)[25])(smem + 13408);
    float (*Y2a)[25]  = (float(*)[25])(smem + 16208);
    float (*z2T)[29]  = (float(*)[29])(smem);
    float (*b1LH)[30] = (float(*)[30])(smem + 3328);
    float (*b1HL)[30] = (float(*)[30])(smem + 6688);
    float (*b1HH)[30] = (float(*)[30])(smem + 10048);
    float (*Y1b)[29]  = (float(*)[29])(smem + 21744);
    float (*Y2b)[29]  = (float(*)[29])(smem + 25920);
    float (*z1T)[37]  = (float(*)[37])(smem);
    float (*b0LH)[38] = (float(*)[38])(smem + 5328);
    float (*b0HL)[38] = (float(*)[38])(smem + 10800);
    float (*b0HH)[38] = (float(*)[38])(smem + 16272);
    float (*Y1c)[37]  = (float(*)[37])(smem + 21744);
    float (*Y2c)[37]  = (float(*)[37])(smem + 26480);

    float A[10];
    #pragma unroll
    for (int t = 0; t < 10; ++t) A[t] = ldT(g0a_ + t);
    float g0[3], g1[5];
    #pragma unroll
    for (int t = 0; t < 3; ++t) g0[t] = ldT(g0o_ + t);
    #pragma unroll
    for (int t = 0; t < 5; ++t) g1[t] = ldT(g1o_ + t);

    // ---- S0: yl tile (24x24, raw origin R0/4-8) + level-2 bands ----
    {
        const size_t ybase = (size_t)b * 64 * 64;
        const int OYr = (R0 >> 2) - 8, OYc = (C0 >> 2) - 8;
        for (int idx = tid; idx < 576; idx += 256){
            int rr = idx / 24, cc = idx % 24;
            int gr = refl(OYr + rr, 64), gc = refl(OYc + cc, 64);
            ylT[rr][cc] = ldT(yl + ybase + gr*64 + gc);
        }
        band_cells<T,12,26>(yh2, b, 32, (R0>>3)-4, (C0>>3)-4,
                            &b2LH[0][0], &b2HL[0][0], &b2HH[0][0], tid);
    }
    __syncthreads();

    // ---- S1: col-ifilt L2 -> Y1a/Y2a (28 rows x 24 cols) ----
    // Thread owns one output row d = tid>>3 (d<28); cols e = (tid&7)*3 + {0,1,2}.
    {
        int d = tid >> 3;
        if (d < 28){
            int zb, bb; float hz[5], hb[5];
            line_setup(A, refl((R0 >> 1) - 6 + d, 128), (R0 >> 2) - 8, zb, bb, hz, hb);
            int e0 = (tid & 7) * 3;
            #pragma unroll
            for (int c = 0; c < 3; ++c){
                int e = e0 + c;
                float s1 = 0.f, s2 = 0.f;
                #pragma unroll
                for (int k = 0; k < 5; ++k){
                    int zr = zb + 2*k, br = bb + 2*k;
                    s1 += hz[k]*ylT[zr][e]  + hb[k]*b2LH[br][e];
                    s2 += hz[k]*b2HL[zr][e] + hb[k]*b2HH[br][e];
                }
                Y1a[d][e] = s1; Y2a[d][e] = s2;
            }
        }
    }
    __syncthreads();

    // ---- S2: row-ifilt L2 -> z2T (28x28); S3: level-1 bands ----
    // Thread owns one output column e = tid>>3 (e<28); rows d = (tid&7) + 8j.
    {
        int e = tid >> 3;
        if (e < 28){
            int zb, bb; float hz[5], hb[5];
            line_setup(A, refl((C0 >> 1) - 6 + e, 128), (C0 >> 2) - 8, zb, bb, hz, hb);
            #pragma unroll
            for (int j = 0; j < 4; ++j){
                int d = (tid & 7) + 8*j;
                if (d < 28){
                    float s = 0.f;
                    #pragma unroll
                    for (int k = 0; k < 5; ++k)
                        s += hz[k]*Y1a[d][zb+2*k] + hb[k]*Y2a[d][bb+2*k];
                    z2T[d][e] = s;
                }
            }
        }
    }
    band_cells<T,14,30>(yh1, b, 64, (R0>>2)-3, (C0>>2)-3,
                        &b1LH[0][0], &b1HL[0][0], &b1HH[0][0], tid);
    __syncthreads();

    // ---- S4: col-ifilt L1 -> Y1b/Y2b (36 rows x 28 cols) ----
    // Thread owns row d = tid/7 (tid<252); cols e = (tid%7)*4 + {0..3}. Exact 36x28.
    {
        if (tid < 252){
            int d = tid / 7, r7 = tid - 7*d;
            int zb, bb; float hz[5], hb[5];
            line_setup(A, refl(R0 - 2 + d, 256), (R0 >> 1) - 6, zb, bb, hz, hb);
            int e0 = r7 * 4;
            #pragma unroll
            for (int c = 0; c < 4; ++c){
                int e = e0 + c;
                float s1 = 0.f, s2 = 0.f;
                #pragma unroll
                for (int k = 0; k < 5; ++k){
                    int zr = zb + 2*k, br = bb + 2*k;
                    s1 += hz[k]*z2T[zr][e]  + hb[k]*b1LH[br][e];
                    s2 += hz[k]*b1HL[zr][e] + hb[k]*b1HH[br][e];
                }
                Y1b[d][e] = s1; Y2b[d][e] = s2;
            }
        }
    }
    __syncthreads();

    // ---- S5: row-ifilt L1 -> z1T (36x36); S6: level-0 bands ----
    // Thread owns column e = tid/7 (tid<252); rows d = (tid%7) + 7j.
    {
        if (tid < 252){
            int e = tid / 7, r7 = tid - 7*e;
            int zb, bb; float hz[5], hb[5];
            line_setup(A, refl(C0 - 2 + e, 256), (C0 >> 1) - 6, zb, bb, hz, hb);
            #pragma unroll
            for (int j = 0; j < 6; ++j){
                int d = r7 + 7*j;
                if (d < 36){
                    float s = 0.f;
                    #pragma unroll
                    for (int k = 0; k < 5; ++k)
                        s += hz[k]*Y1b[d][zb+2*k] + hb[k]*Y2b[d][bb+2*k];
                    z1T[d][e] = s;
                }
            }
        }
    }
    band_cells<T,18,38>(yh0, b, 128, (R0>>1)-1, (C0>>1)-1,
                        &b0LH[0][0], &b0HL[0][0], &b0HH[0][0], tid);
    __syncthreads();

    // ---- S7: level-0 column filter (verbatim) ----
    for (int idx = tid; idx < 1152; idx += 256){
        int u = idx / 36, m = idx % 36;
        float s1 = 0.f, s2 = 0.f;
        #pragma unroll
        for (int k = 0; k < 3; ++k){
            s1 += g0[2-k] * z1T[u+1+k][m];
            s2 += g0[2-k] * b0HL[u+1+k][m];
        }
        #pragma unroll
        for (int k = 0; k < 5; ++k){
            s1 += g1[4-k] * b0LH[u+k][m];
            s2 += g1[4-k] * b0HH[u+k][m];
        }
        Y1c[u][m] = s1; Y2c[u][m] = s2;
    }
    __syncthreads();

    // ---- S8: level-0 row filter + store (verbatim) ----
    int u  = tid >> 3;
    int vb = (tid & 7) * 4;
    float o[4];
    #pragma unroll
    for (int j = 0; j < 4; ++j){
        int v = vb + j;
        float acc = 0.f;
        #pragma unroll
        for (int k = 0; k < 3; ++k) acc += g0[2-k] * Y1c[u][v+1+k];
        #pragma unroll
        for (int k = 0; k < 5; ++k) acc += g1[4-k] * Y2c[u][v+k];
        o[j] = acc;
    }
    store4(out, ((size_t)b*256 + R0 + u)*256 + C0 + vb, o[0], o[1], o[2], o[3]);
}

__global__ __launch_bounds__(256)
void kdtcwt(const void* yl, const void* yh0, const void* yh1, const void* yh2,
            const void* g0a, const void* g0o, const void* g1o, void* out)
{
    __shared__ __align__(16) char smem[FUSED_SMEM];
    // dtype detect from g0o word 0: bf16 packing puts bf16(0.70710678)=0x3F35 in the
    // high half; f32(0.35355339)=0x3EB504F3 has high half 0x3EB5. Block-uniform branch.
    unsigned w0 = *(const unsigned*)g0o;
    if ((w0 >> 16) == 0x3F35u)
        dtbody<bf16>(smem, (const bf16*)yl, (const bf16*)yh0, (const bf16*)yh1,
                     (const bf16*)yh2, (const bf16*)g0a, (const bf16*)g0o,
                     (const bf16*)g1o, (bf16*)out);
    else
        dtbody<float>(smem, (const float*)yl, (const float*)yh0, (const float*)yh1,
                      (const float*)yh2, (const float*)g0a, (const float*)g0o,
                      (const float*)g1o, (float*)out);
}

extern "C" void kernel_launch(void* const* d_in, const int* in_sizes, int n_in,
                              void* d_out, int out_size, void* d_ws, size_t ws_size,
                              hipStream_t stream) {
    const void* yl  = d_in[0];
    const void* yh0 = d_in[1];
    const void* yh1 = d_in[2];
    const void* yh2 = d_in[3];
    const void* g0o = d_in[4];
    const void* g1o = d_in[5];
    const void* g0a = d_in[6];
    // g0b/g1a/g1b (d_in[7..9]) are derived from g0a inside the kernel.

    kdtcwt<<<dim3(8, 8, 128), 256, 0, stream>>>(yl, yh0, yh1, yh2, g0a, g0o, g1o, d_out);
}

// Round 7
// 253.701 us; speedup vs baseline: 1.1757x; 1.1757x over previous
//
#include <hip/hip_runtime.h>
#include <hip/hip_bf16.h>

typedef __hip_bfloat16 bf16;

__device__ __forceinline__ float ldT(const bf16* p){ return __bfloat162float(*p); }
__device__ __forceinline__ float ldT(const float* p){ return *p; }

// load 2 consecutive elements (r,i pair) as float2
__device__ __forceinline__ float2 ld2T(const bf16* p){
    unsigned v = *(const unsigned*)p;          // [hi | lo] little-endian
    float2 r;
    r.x = __uint_as_float(v << 16);            // low bf16 -> f32 (exact)
    r.y = __uint_as_float(v & 0xFFFF0000u);    // high bf16 -> f32
    return r;
}
__device__ __forceinline__ float2 ld2T(const float* p){ return *(const float2*)p; }

__device__ __forceinline__ int refl(int i, int n){
    if (i < 0) return -1 - i;
    if (i >= n) return 2*n - 1 - i;
    return i;
}

__device__ __forceinline__ void store4(bf16* out, size_t idx,
                                       float o0, float o1, float o2, float o3){
    union { ushort4 u4; bf16 h[4]; } pk;
    pk.h[0] = __float2bfloat16(o0); pk.h[1] = __float2bfloat16(o1);
    pk.h[2] = __float2bfloat16(o2); pk.h[3] = __float2bfloat16(o3);
    *(ushort4*)(out + idx) = pk.u4;
}
__device__ __forceinline__ void store4(float* out, size_t idx,
                                       float o0, float o1, float o2, float o3){
    float4 st; st.x=o0; st.y=o1; st.z=o2; st.w=o3;
    *(float4*)(out + idx) = st;
}

// Write one 2x2 c2q cell. fr/fc = reflection parity flips for row/col.
__device__ __forceinline__ void wcell(float* B, int stride, int r0, int c0,
                                      int fr, int fc, float2 P, float2 Q){
    const float s = 0.70710678118654752f;
    float v00=(P.x+Q.x)*s, v01=(P.y+Q.y)*s, v10=(P.y-Q.y)*s, v11=(Q.x-P.x)*s;
    float t0 = fr ? v10 : v00, t1 = fr ? v11 : v01;   // row r0  : pu = fr
    float u0 = fr ? v00 : v10, u1 = fr ? v01 : v11;   // row r0+1: pu = 1^fr
    float2 w0 = fc ? make_float2(t1, t0) : make_float2(t0, t1);
    float2 w1 = fc ? make_float2(u1, u0) : make_float2(u0, u1);
    *(float2*)(B + r0*stride + c0)     = w0;
    *(float2*)(B + (r0+1)*stride + c0) = w1;
}

// Generate the symmetric-extended band tiles (LH,HL,HH) cell-wise.
template<typename T, int NC, int STRIDE>
__device__ __forceinline__ void band_cells(const T* yh, int b, int hs,
    int cor, int coc, float* LH, float* HL, float* HH, int tid){
    const size_t sstr = (size_t)hs * hs;
    const size_t ybase = (size_t)b * 6 * sstr;
    for (int idx = tid; idx < NC*NC; idx += 256){
        int i = idx / NC, j = idx % NC;
        int cr = cor + i; int fr = (cr < 0) | (cr >= hs); if (fr) cr = refl(cr, hs);
        int cc = coc + j; int fc = (cc < 0) | (cc >= hs); if (fc) cc = refl(cc, hs);
        size_t base = ybase + (size_t)cr*hs + cc;
        float2 a0 = ld2T(yh + 2*base);
        float2 a1 = ld2T(yh + 2*(base +   sstr));
        float2 a2 = ld2T(yh + 2*(base + 2*sstr));
        float2 a3 = ld2T(yh + 2*(base + 3*sstr));
        float2 a4 = ld2T(yh + 2*(base + 4*sstr));
        float2 a5 = ld2T(yh + 2*(base + 5*sstr));
        wcell(LH, STRIDE, 2*i, 2*j, fr, fc, a0, a5);
        wcell(HL, STRIDE, 2*i, 2*j, fr, fc, a2, a3);
        wcell(HH, STRIDE, 2*i, 2*j, fr, fc, a1, a4);
    }
}

__device__ __forceinline__ float xsgn(float f, unsigned s){
    return __uint_as_float(__float_as_uint(f) ^ s);
}

// Per-line tap setup -> 12 NAMED SCALARS (no local arrays -> no scratch).
// Tap algebra (verified round 2/4):
//   q=0: hz=A[1+2k]  hb=-A[8-2k] | q=1: hz=A[8-2k]  hb= A[1+2k]
//   q=2: hz=A[2k]    hb= A[9-2k] | q=3: hz=A[9-2k]  hb=-A[2k]
// Identity: hz = qa? v : u, |hb| = qa? u : v with u=q1?A[2k]:A[1+2k],
// v=q1?A[9-2k]:A[8-2k]; sign(hb) = -1 iff qa==q1. (checked for all 4 q rows)
__device__ __forceinline__ void line_setup(const float (&A)[10], int G, int off,
    int& zb, int& bb,
    float& z0, float& z1, float& z2, float& z3, float& z4,
    float& b0, float& b1, float& b2, float& b3, float& b4)
{
    int t = G >> 2, q = G & 3;
    int qa = q & 1;
    bool q1 = q >= 2;
    zb = 2*t - 4 + qa - off;
    bb = 2*t - 3 - qa - off;
    unsigned sg = ((q1 ? 1 : 0) == qa) ? 0x80000000u : 0u;
    float u, v;
    u = q1 ? A[0] : A[1]; v = q1 ? A[9] : A[8];  z0 = qa ? v : u;  b0 = xsgn(qa ? u : v, sg);
    u = q1 ? A[2] : A[3]; v = q1 ? A[7] : A[6];  z1 = qa ? v : u;  b1 = xsgn(qa ? u : v, sg);
    u = q1 ? A[4] : A[5]; v = q1 ? A[5] : A[4];  z2 = qa ? v : u;  b2 = xsgn(qa ? u : v, sg);
    u = q1 ? A[6] : A[7]; v = q1 ? A[3] : A[2];  z3 = qa ? v : u;  b3 = xsgn(qa ? u : v, sg);
    u = q1 ? A[8] : A[9]; v = q1 ? A[1] : A[0];  z4 = qa ? v : u;  b4 = xsgn(qa ? u : v, sg);
}

#define LINEVARS int zb, bbb; float tz0,tz1,tz2,tz3,tz4, tb0,tb1,tb2,tb3,tb4

// LDS layout (bytes), stage-lifetime aliased; peak 31216 (unchanged)
#define FUSED_SMEM 31216

template<typename T>
__device__ void dtbody(char* smem, const T* yl, const T* yh0, const T* yh1, const T* yh2,
                       const T* g0a_, const T* g0o_, const T* g1o_, T* out)
{
    const int b  = blockIdx.z;
    const int R0 = blockIdx.y * 32, C0 = blockIdx.x * 32;
    const int tid = threadIdx.x;

    float (*ylT)[26]  = (float(*)[26])(smem);
    float (*b2LH)[26] = (float(*)[26])(smem + 2496);
    float (*b2HL)[26] = (float(*)[26])(smem + 4992);
    float (*b2HH)[26] = (float(*)[26])(smem + 7488);
    float (*Y1a)[25]  = (float(*)[25])(smem + 13408);
    float (*Y2a)[25]  = (float(*)[25])(smem + 16208);
    float (*z2T)[29]  = (float(*)[29])(smem);
    float (*b1LH)[30] = (float(*)[30])(smem + 3328);
    float (*b1HL)[30] = (float(*)[30])(smem + 6688);
    float (*b1HH)[30] = (float(*)[30])(smem + 10048);
    float (*Y1b)[29]  = (float(*)[29])(smem + 21744);
    float (*Y2b)[29]  = (float(*)[29])(smem + 25920);
    float (*z1T)[37]  = (float(*)[37])(smem);
    float (*b0LH)[38] = (float(*)[38])(smem + 5328);
    float (*b0HL)[38] = (float(*)[38])(smem + 10800);
    float (*b0HH)[38] = (float(*)[38])(smem + 16272);
    float (*Y1c)[37]  = (float(*)[37])(smem + 21744);
    float (*Y2c)[37]  = (float(*)[37])(smem + 26480);

    float A[10];
    #pragma unroll
    for (int t = 0; t < 10; ++t) A[t] = ldT(g0a_ + t);
    float g0[3], g1[5];
    #pragma unroll
    for (int t = 0; t < 3; ++t) g0[t] = ldT(g0o_ + t);
    #pragma unroll
    for (int t = 0; t < 5; ++t) g1[t] = ldT(g1o_ + t);

    // ---- S0: yl tile (24x24, raw origin R0/4-8) + level-2 bands ----
    {
        const size_t ybase = (size_t)b * 64 * 64;
        const int OYr = (R0 >> 2) - 8, OYc = (C0 >> 2) - 8;
        for (int idx = tid; idx < 576; idx += 256){
            int rr = idx / 24, cc = idx % 24;
            int gr = refl(OYr + rr, 64), gc = refl(OYc + cc, 64);
            ylT[rr][cc] = ldT(yl + ybase + gr*64 + gc);
        }
        band_cells<T,12,26>(yh2, b, 32, (R0>>3)-4, (C0>>3)-4,
                            &b2LH[0][0], &b2HL[0][0], &b2HH[0][0], tid);
    }
    __syncthreads();

    // ---- S1: col-ifilt L2 -> Y1a/Y2a (28 rows x 24 cols) ----
    // Thread owns row d = tid>>3 (d<28); cols e = (tid&7)*3 + {0,1,2}.
    {
        int d = tid >> 3;
        if (d < 28){
            LINEVARS;
            line_setup(A, refl((R0 >> 1) - 6 + d, 128), (R0 >> 2) - 8,
                       zb, bbb, tz0,tz1,tz2,tz3,tz4, tb0,tb1,tb2,tb3,tb4);
            int e0 = (tid & 7) * 3;
            #pragma unroll
            for (int c = 0; c < 3; ++c){
                int e = e0 + c;
                float s1 = tz0*ylT[zb  ][e] + tz1*ylT[zb+2][e] + tz2*ylT[zb+4][e]
                         + tz3*ylT[zb+6][e] + tz4*ylT[zb+8][e]
                         + tb0*b2LH[bbb  ][e] + tb1*b2LH[bbb+2][e] + tb2*b2LH[bbb+4][e]
                         + tb3*b2LH[bbb+6][e] + tb4*b2LH[bbb+8][e];
                float s2 = tz0*b2HL[zb  ][e] + tz1*b2HL[zb+2][e] + tz2*b2HL[zb+4][e]
                         + tz3*b2HL[zb+6][e] + tz4*b2HL[zb+8][e]
                         + tb0*b2HH[bbb  ][e] + tb1*b2HH[bbb+2][e] + tb2*b2HH[bbb+4][e]
                         + tb3*b2HH[bbb+6][e] + tb4*b2HH[bbb+8][e];
                Y1a[d][e] = s1; Y2a[d][e] = s2;
            }
        }
    }
    __syncthreads();

    // ---- S2: row-ifilt L2 -> z2T (28x28); S3: level-1 bands ----
    // Thread owns column e = tid>>3 (e<28); rows d = (tid&7) + 8j.
    {
        int e = tid >> 3;
        if (e < 28){
            LINEVARS;
            line_setup(A, refl((C0 >> 1) - 6 + e, 128), (C0 >> 2) - 8,
                       zb, bbb, tz0,tz1,tz2,tz3,tz4, tb0,tb1,tb2,tb3,tb4);
            #pragma unroll
            for (int j = 0; j < 4; ++j){
                int d = (tid & 7) + 8*j;
                if (d < 28){
                    float s = tz0*Y1a[d][zb  ] + tz1*Y1a[d][zb+2] + tz2*Y1a[d][zb+4]
                            + tz3*Y1a[d][zb+6] + tz4*Y1a[d][zb+8]
                            + tb0*Y2a[d][bbb  ] + tb1*Y2a[d][bbb+2] + tb2*Y2a[d][bbb+4]
                            + tb3*Y2a[d][bbb+6] + tb4*Y2a[d][bbb+8];
                    z2T[d][e] = s;
                }
            }
        }
    }
    band_cells<T,14,30>(yh1, b, 64, (R0>>2)-3, (C0>>2)-3,
                        &b1LH[0][0], &b1HL[0][0], &b1HH[0][0], tid);
    __syncthreads();

    // ---- S4: col-ifilt L1 -> Y1b/Y2b (36 rows x 28 cols) ----
    // Thread owns row d = tid/7 (tid<252); cols e = (tid%7)*4 + {0..3}.
    {
        if (tid < 252){
            int d = tid / 7, r7 = tid - 7*d;
            LINEVARS;
            line_setup(A, refl(R0 - 2 + d, 256), (R0 >> 1) - 6,
                       zb, bbb, tz0,tz1,tz2,tz3,tz4, tb0,tb1,tb2,tb3,tb4);
            int e0 = r7 * 4;
            #pragma unroll
            for (int c = 0; c < 4; ++c){
                int e = e0 + c;
                float s1 = tz0*z2T[zb  ][e] + tz1*z2T[zb+2][e] + tz2*z2T[zb+4][e]
                         + tz3*z2T[zb+6][e] + tz4*z2T[zb+8][e]
                         + tb0*b1LH[bbb  ][e] + tb1*b1LH[bbb+2][e] + tb2*b1LH[bbb+4][e]
                         + tb3*b1LH[bbb+6][e] + tb4*b1LH[bbb+8][e];
                float s2 = tz0*b1HL[zb  ][e] + tz1*b1HL[zb+2][e] + tz2*b1HL[zb+4][e]
                         + tz3*b1HL[zb+6][e] + tz4*b1HL[zb+8][e]
                         + tb0*b1HH[bbb  ][e] + tb1*b1HH[bbb+2][e] + tb2*b1HH[bbb+4][e]
                         + tb3*b1HH[bbb+6][e] + tb4*b1HH[bbb+8][e];
                Y1b[d][e] = s1; Y2b[d][e] = s2;
            }
        }
    }
    __syncthreads();

    // ---- S5: row-ifilt L1 -> z1T (36x36); S6: level-0 bands ----
    // Thread owns column e = tid/7 (tid<252); rows d = (tid%7) + 7j.
    {
        if (tid < 252){
            int e = tid / 7, r7 = tid - 7*e;
            LINEVARS;
            line_setup(A, refl(C0 - 2 + e, 256), (C0 >> 1) - 6,
                       zb, bbb, tz0,tz1,tz2,tz3,tz4, tb0,tb1,tb2,tb3,tb4);
            #pragma unroll
            for (int j = 0; j < 6; ++j){
                int d = r7 + 7*j;
                if (d < 36){
                    float s = tz0*Y1b[d][zb  ] + tz1*Y1b[d][zb+2] + tz2*Y1b[d][zb+4]
                            + tz3*Y1b[d][zb+6] + tz4*Y1b[d][zb+8]
                            + tb0*Y2b[d][bbb  ] + tb1*Y2b[d][bbb+2] + tb2*Y2b[d][bbb+4]
                            + tb3*Y2b[d][bbb+6] + tb4*Y2b[d][bbb+8];
                    z1T[d][e] = s;
                }
            }
        }
    }
    band_cells<T,18,38>(yh0, b, 128, (R0>>1)-1, (C0>>1)-1,
                        &b0LH[0][0], &b0HL[0][0], &b0HH[0][0], tid);
    __syncthreads();

    // ---- S7: level-0 column filter (verbatim) ----
    for (int idx = tid; idx < 1152; idx += 256){
        int u = idx / 36, m = idx % 36;
        float s1 = 0.f, s2 = 0.f;
        #pragma unroll
        for (int k = 0; k < 3; ++k){
            s1 += g0[2-k] * z1T[u+1+k][m];
            s2 += g0[2-k] * b0HL[u+1+k][m];
        }
        #pragma unroll
        for (int k = 0; k < 5; ++k){
            s1 += g1[4-k] * b0LH[u+k][m];
            s2 += g1[4-k] * b0HH[u+k][m];
        }
        Y1c[u][m] = s1; Y2c[u][m] = s2;
    }
    __syncthreads();

    // ---- S8: level-0 row filter + store (verbatim) ----
    int u  = tid >> 3;
    int vb = (tid & 7) * 4;
    float o[4];
    #pragma unroll
    for (int j = 0; j < 4; ++j){
        int v = vb + j;
        float acc = 0.f;
        #pragma unroll
        for (int k = 0; k < 3; ++k) acc += g0[2-k] * Y1c[u][v+1+k];
        #pragma unroll
        for (int k = 0; k < 5; ++k) acc += g1[4-k] * Y2c[u][v+k];
        o[j] = acc;
    }
    store4(out, ((size_t)b*256 + R0 + u)*256 + C0 + vb, o[0], o[1], o[2], o[3]);
}

__global__ __launch_bounds__(256)
void kdtcwt(const void* yl, const void* yh0, const void* yh1, const void* yh2,
            const void* g0a, const void* g0o, const void* g1o, void* out)
{
    __shared__ __align__(16) char smem[FUSED_SMEM];
    // dtype detect from g0o word 0: bf16 packing puts bf16(0.70710678)=0x3F35 in the
    // high half; f32(0.35355339)=0x3EB504F3 has high half 0x3EB5. Block-uniform branch.
    unsigned w0 = *(const unsigned*)g0o;
    if ((w0 >> 16) == 0x3F35u)
        dtbody<bf16>(smem, (const bf16*)yl, (const bf16*)yh0, (const bf16*)yh1,
                     (const bf16*)yh2, (const bf16*)g0a, (const bf16*)g0o,
                     (const bf16*)g1o, (bf16*)out);
    else
        dtbody<float>(smem, (const float*)yl, (const float*)yh0, (const float*)yh1,
                      (const float*)yh2, (const float*)g0a, (const float*)g0o,
                      (const float*)g1o, (float*)out);
}

extern "C" void kernel_launch(void* const* d_in, const int* in_sizes, int n_in,
                              void* d_out, int out_size, void* d_ws, size_t ws_size,
                              hipStream_t stream) {
    const void* yl  = d_in[0];
    const void* yh0 = d_in[1];
    const void* yh1 = d_in[2];
    const void* yh2 = d_in[3];
    const void* g0o = d_in[4];
    const void* g1o = d_in[5];
    const void* g0a = d_in[6];
    // g0b/g1a/g1b (d_in[7..9]) are derived from g0a inside the kernel.

    kdtcwt<<<dim3(8, 8, 128), 256, 0, stream>>>(yl, yh0, yh1, yh2, g0a, g0o, g1o, d_out);
}

// Round 8
// 244.072 us; speedup vs baseline: 1.2221x; 1.0395x over previous
//
#include <hip/hip_runtime.h>
#include <hip/hip_bf16.h>

typedef __hip_bfloat16 bf16;

__device__ __forceinline__ float ldT(const bf16* p){ return __bfloat162float(*p); }
__device__ __forceinline__ float ldT(const float* p){ return *p; }

// load 2 consecutive elements (r,i pair) as float2
__device__ __forceinline__ float2 ld2T(const bf16* p){
    unsigned v = *(const unsigned*)p;          // [hi | lo] little-endian
    float2 r;
    r.x = __uint_as_float(v << 16);            // low bf16 -> f32 (exact)
    r.y = __uint_as_float(v & 0xFFFF0000u);    // high bf16 -> f32
    return r;
}
__device__ __forceinline__ float2 ld2T(const float* p){ return *(const float2*)p; }

__device__ __forceinline__ int refl(int i, int n){
    if (i < 0) return -1 - i;
    if (i >= n) return 2*n - 1 - i;
    return i;
}

__device__ __forceinline__ void store4(bf16* out, size_t idx,
                                       float o0, float o1, float o2, float o3){
    union { ushort4 u4; bf16 h[4]; } pk;
    pk.h[0] = __float2bfloat16(o0); pk.h[1] = __float2bfloat16(o1);
    pk.h[2] = __float2bfloat16(o2); pk.h[3] = __float2bfloat16(o3);
    *(ushort4*)(out + idx) = pk.u4;
}
__device__ __forceinline__ void store4(float* out, size_t idx,
                                       float o0, float o1, float o2, float o3){
    float4 st; st.x=o0; st.y=o1; st.z=o2; st.w=o3;
    *(float4*)(out + idx) = st;
}

// Write one 2x2 c2q cell. fr/fc = reflection parity flips for row/col.
__device__ __forceinline__ void wcell(float* B, int stride, int r0, int c0,
                                      int fr, int fc, float2 P, float2 Q){
    const float s = 0.70710678118654752f;
    float v00=(P.x+Q.x)*s, v01=(P.y+Q.y)*s, v10=(P.y-Q.y)*s, v11=(Q.x-P.x)*s;
    float t0 = fr ? v10 : v00, t1 = fr ? v11 : v01;   // row r0  : pu = fr
    float u0 = fr ? v00 : v10, u1 = fr ? v01 : v11;   // row r0+1: pu = 1^fr
    float2 w0 = fc ? make_float2(t1, t0) : make_float2(t0, t1);
    float2 w1 = fc ? make_float2(u1, u0) : make_float2(u0, u1);
    *(float2*)(B + r0*stride + c0)     = w0;
    *(float2*)(B + (r0+1)*stride + c0) = w1;
}

// Generate the symmetric-extended band tiles (LH,HL,HH) cell-wise.
template<typename T, int NC, int STRIDE>
__device__ __forceinline__ void band_cells(const T* yh, int b, int hs,
    int cor, int coc, float* LH, float* HL, float* HH, int tid){
    const size_t sstr = (size_t)hs * hs;
    const size_t ybase = (size_t)b * 6 * sstr;
    for (int idx = tid; idx < NC*NC; idx += 256){
        int i = idx / NC, j = idx % NC;
        int cr = cor + i; int fr = (cr < 0) | (cr >= hs); if (fr) cr = refl(cr, hs);
        int cc = coc + j; int fc = (cc < 0) | (cc >= hs); if (fc) cc = refl(cc, hs);
        size_t base = ybase + (size_t)cr*hs + cc;
        float2 a0 = ld2T(yh + 2*base);
        float2 a1 = ld2T(yh + 2*(base +   sstr));
        float2 a2 = ld2T(yh + 2*(base + 2*sstr));
        float2 a3 = ld2T(yh + 2*(base + 3*sstr));
        float2 a4 = ld2T(yh + 2*(base + 4*sstr));
        float2 a5 = ld2T(yh + 2*(base + 5*sstr));
        wcell(LH, STRIDE, 2*i, 2*j, fr, fc, a0, a5);
        wcell(HL, STRIDE, 2*i, 2*j, fr, fc, a2, a3);
        wcell(HH, STRIDE, 2*i, 2*j, fr, fc, a1, a4);
    }
}

__device__ __forceinline__ float xsgn(float f, unsigned s){
    return __uint_as_float(__float_as_uint(f) ^ s);
}

// Per-line tap setup -> 12 NAMED SCALARS (no local arrays -> no scratch).
// Tap algebra (verified round 2/4):
//   q=0: hz=A[1+2k]  hb=-A[8-2k] | q=1: hz=A[8-2k]  hb= A[1+2k]
//   q=2: hz=A[2k]    hb= A[9-2k] | q=3: hz=A[9-2k]  hb=-A[2k]
__device__ __forceinline__ void line_setup(const float (&A)[10], int G, int off,
    int& zb, int& bb,
    float& z0, float& z1, float& z2, float& z3, float& z4,
    float& b0, float& b1, float& b2, float& b3, float& b4)
{
    int t = G >> 2, q = G & 3;
    int qa = q & 1;
    bool q1 = q >= 2;
    zb = 2*t - 4 + qa - off;
    bb = 2*t - 3 - qa - off;
    unsigned sg = ((q1 ? 1 : 0) == qa) ? 0x80000000u : 0u;
    float u, v;
    u = q1 ? A[0] : A[1]; v = q1 ? A[9] : A[8];  z0 = qa ? v : u;  b0 = xsgn(qa ? u : v, sg);
    u = q1 ? A[2] : A[3]; v = q1 ? A[7] : A[6];  z1 = qa ? v : u;  b1 = xsgn(qa ? u : v, sg);
    u = q1 ? A[4] : A[5]; v = q1 ? A[5] : A[4];  z2 = qa ? v : u;  b2 = xsgn(qa ? u : v, sg);
    u = q1 ? A[6] : A[7]; v = q1 ? A[3] : A[2];  z3 = qa ? v : u;  b3 = xsgn(qa ? u : v, sg);
    u = q1 ? A[8] : A[9]; v = q1 ? A[1] : A[0];  z4 = qa ? v : u;  b4 = xsgn(qa ? u : v, sg);
}

#define LINEVARS int zb, bbb; float tz0,tz1,tz2,tz3,tz4, tb0,tb1,tb2,tb3,tb4

// LDS layout (bytes), stage-lifetime aliased; peak 31216.
// Strides retuned for bank-conflict freedom (S1 lane pattern: 4 distinct rows
// x col-stride-3 lanes -> stride 24 gives 24*dz mod 32 in {8,16,24}, never a
// multiple-of-3 residue -> clean):
//  A: ylT @0 (24x24=2304), b2LH @2304, b2HL @4608, b2HH @6912 (end 9216)
//  B: Y1a @13328 (28x24=2688), Y2a @16016 (end 18704)
//  C: z2T @0 (28x29=3248), b1LH @3248 (28x30=3360), b1HL @6608, b1HH @9968 (end 13328)
//  D: Y1b @21744 (36x29=4176), Y2b @25920 (end 30096)
//  E: z1T @0 (36x37=5328), b0LH @5328 (36x38=5472), b0HL @10800, b0HH @16272 (end 21744)
//  F: Y1c @21744 (32x37=4736), Y2c @26480 (end 31216)
#define FUSED_SMEM 31216

template<typename T>
__device__ void dtbody(char* smem, const T* yl, const T* yh0, const T* yh1, const T* yh2,
                       const T* g0a_, const T* g0o_, const T* g1o_, T* out)
{
    const int b  = blockIdx.z;
    const int R0 = blockIdx.y * 32, C0 = blockIdx.x * 32;
    const int tid = threadIdx.x;

    float (*ylT)[24]  = (float(*)[24])(smem);
    float (*b2LH)[24] = (float(*)[24])(smem + 2304);
    float (*b2HL)[24] = (float(*)[24])(smem + 4608);
    float (*b2HH)[24] = (float(*)[24])(smem + 6912);
    float (*Y1a)[24]  = (float(*)[24])(smem + 13328);
    float (*Y2a)[24]  = (float(*)[24])(smem + 16016);
    float (*z2T)[29]  = (float(*)[29])(smem);
    float (*b1LH)[30] = (float(*)[30])(smem + 3248);
    float (*b1HL)[30] = (float(*)[30])(smem + 6608);
    float (*b1HH)[30] = (float(*)[30])(smem + 9968);
    float (*Y1b)[29]  = (float(*)[29])(smem + 21744);
    float (*Y2b)[29]  = (float(*)[29])(smem + 25920);
    float (*z1T)[37]  = (float(*)[37])(smem);
    float (*b0LH)[38] = (float(*)[38])(smem + 5328);
    float (*b0HL)[38] = (float(*)[38])(smem + 10800);
    float (*b0HH)[38] = (float(*)[38])(smem + 16272);
    float (*Y1c)[37]  = (float(*)[37])(smem + 21744);
    float (*Y2c)[37]  = (float(*)[37])(smem + 26480);

    float A[10];
    #pragma unroll
    for (int t = 0; t < 10; ++t) A[t] = ldT(g0a_ + t);
    float g0[3], g1[5];
    #pragma unroll
    for (int t = 0; t < 3; ++t) g0[t] = ldT(g0o_ + t);
    #pragma unroll
    for (int t = 0; t < 5; ++t) g1[t] = ldT(g1o_ + t);

    // ---- S0: yl tile (24x24, raw origin R0/4-8) + level-2 bands ----
    {
        const size_t ybase = (size_t)b * 64 * 64;
        const int OYr = (R0 >> 2) - 8, OYc = (C0 >> 2) - 8;
        for (int idx = tid; idx < 576; idx += 256){
            int rr = idx / 24, cc = idx % 24;
            int gr = refl(OYr + rr, 64), gc = refl(OYc + cc, 64);
            ylT[rr][cc] = ldT(yl + ybase + gr*64 + gc);
        }
        band_cells<T,12,24>(yh2, b, 32, (R0>>3)-4, (C0>>3)-4,
                            &b2LH[0][0], &b2HL[0][0], &b2HH[0][0], tid);
    }
    __syncthreads();

    // ---- S1: col-ifilt L2 -> Y1a/Y2a (28 rows x 24 cols) ----
    // Thread owns row d = tid>>3 (d<28); cols e = (tid&7)*3 + {0,1,2}.
    {
        int d = tid >> 3;
        if (d < 28){
            LINEVARS;
            line_setup(A, refl((R0 >> 1) - 6 + d, 128), (R0 >> 2) - 8,
                       zb, bbb, tz0,tz1,tz2,tz3,tz4, tb0,tb1,tb2,tb3,tb4);
            int e0 = (tid & 7) * 3;
            #pragma unroll
            for (int c = 0; c < 3; ++c){
                int e = e0 + c;
                float s1 = tz0*ylT[zb  ][e] + tz1*ylT[zb+2][e] + tz2*ylT[zb+4][e]
                         + tz3*ylT[zb+6][e] + tz4*ylT[zb+8][e]
                         + tb0*b2LH[bbb  ][e] + tb1*b2LH[bbb+2][e] + tb2*b2LH[bbb+4][e]
                         + tb3*b2LH[bbb+6][e] + tb4*b2LH[bbb+8][e];
                float s2 = tz0*b2HL[zb  ][e] + tz1*b2HL[zb+2][e] + tz2*b2HL[zb+4][e]
                         + tz3*b2HL[zb+6][e] + tz4*b2HL[zb+8][e]
                         + tb0*b2HH[bbb  ][e] + tb1*b2HH[bbb+2][e] + tb2*b2HH[bbb+4][e]
                         + tb3*b2HH[bbb+6][e] + tb4*b2HH[bbb+8][e];
                Y1a[d][e] = s1; Y2a[d][e] = s2;
            }
        }
    }
    __syncthreads();

    // ---- S2: row-ifilt L2 -> z2T (28x28); S3: level-1 bands ----
    // Thread owns column e = tid>>3 (e<28); rows d = (tid&7) + 8j.
    {
        int e = tid >> 3;
        if (e < 28){
            LINEVARS;
            line_setup(A, refl((C0 >> 1) - 6 + e, 128), (C0 >> 2) - 8,
                       zb, bbb, tz0,tz1,tz2,tz3,tz4, tb0,tb1,tb2,tb3,tb4);
            #pragma unroll
            for (int j = 0; j < 4; ++j){
                int d = (tid & 7) + 8*j;
                if (d < 28){
                    float s = tz0*Y1a[d][zb  ] + tz1*Y1a[d][zb+2] + tz2*Y1a[d][zb+4]
                            + tz3*Y1a[d][zb+6] + tz4*Y1a[d][zb+8]
                            + tb0*Y2a[d][bbb  ] + tb1*Y2a[d][bbb+2] + tb2*Y2a[d][bbb+4]
                            + tb3*Y2a[d][bbb+6] + tb4*Y2a[d][bbb+8];
                    z2T[d][e] = s;
                }
            }
        }
    }
    band_cells<T,14,30>(yh1, b, 64, (R0>>2)-3, (C0>>2)-3,
                        &b1LH[0][0], &b1HL[0][0], &b1HH[0][0], tid);
    __syncthreads();

    // ---- S4: col-ifilt L1 -> Y1b/Y2b (36 rows x 28 cols) ----
    // Thread owns row d = tid/7 (tid<252); cols e = (tid%7)*4 + {0..3}.
    {
        if (tid < 252){
            int d = tid / 7, r7 = tid - 7*d;
            LINEVARS;
            line_setup(A, refl(R0 - 2 + d, 256), (R0 >> 1) - 6,
                       zb, bbb, tz0,tz1,tz2,tz3,tz4, tb0,tb1,tb2,tb3,tb4);
            int e0 = r7 * 4;
            #pragma unroll
            for (int c = 0; c < 4; ++c){
                int e = e0 + c;
                float s1 = tz0*z2T[zb  ][e] + tz1*z2T[zb+2][e] + tz2*z2T[zb+4][e]
                         + tz3*z2T[zb+6][e] + tz4*z2T[zb+8][e]
                         + tb0*b1LH[bbb  ][e] + tb1*b1LH[bbb+2][e] + tb2*b1LH[bbb+4][e]
                         + tb3*b1LH[bbb+6][e] + tb4*b1LH[bbb+8][e];
                float s2 = tz0*b1HL[zb  ][e] + tz1*b1HL[zb+2][e] + tz2*b1HL[zb+4][e]
                         + tz3*b1HL[zb+6][e] + tz4*b1HL[zb+8][e]
                         + tb0*b1HH[bbb  ][e] + tb1*b1HH[bbb+2][e] + tb2*b1HH[bbb+4][e]
                         + tb3*b1HH[bbb+6][e] + tb4*b1HH[bbb+8][e];
                Y1b[d][e] = s1; Y2b[d][e] = s2;
            }
        }
    }
    __syncthreads();

    // ---- S5: row-ifilt L1 -> z1T (36x36); S6: level-0 bands ----
    // Thread owns column e = tid/7 (tid<252); rows d = (tid%7) + 7j.
    {
        if (tid < 252){
            int e = tid / 7, r7 = tid - 7*e;
            LINEVARS;
            line_setup(A, refl(C0 - 2 + e, 256), (C0 >> 1) - 6,
                       zb, bbb, tz0,tz1,tz2,tz3,tz4, tb0,tb1,tb2,tb3,tb4);
            #pragma unroll
            for (int j = 0; j < 6; ++j){
                int d = r7 + 7*j;
                if (d < 36){
                    float s = tz0*Y1b[d][zb  ] + tz1*Y1b[d][zb+2] + tz2*Y1b[d][zb+4]
                            + tz3*Y1b[d][zb+6] + tz4*Y1b[d][zb+8]
                            + tb0*Y2b[d][bbb  ] + tb1*Y2b[d][bbb+2] + tb2*Y2b[d][bbb+4]
                            + tb3*Y2b[d][bbb+6] + tb4*Y2b[d][bbb+8];
                    z1T[d][e] = s;
                }
            }
        }
    }
    band_cells<T,18,38>(yh0, b, 128, (R0>>1)-1, (C0>>1)-1,
                        &b0LH[0][0], &b0HL[0][0], &b0HH[0][0], tid);
    __syncthreads();

    // ---- S7: level-0 column filter (verbatim) ----
    for (int idx = tid; idx < 1152; idx += 256){
        int u = idx / 36, m = idx % 36;
        float s1 = 0.f, s2 = 0.f;
        #pragma unroll
        for (int k = 0; k < 3; ++k){
            s1 += g0[2-k] * z1T[u+1+k][m];
            s2 += g0[2-k] * b0HL[u+1+k][m];
        }
        #pragma unroll
        for (int k = 0; k < 5; ++k){
            s1 += g1[4-k] * b0LH[u+k][m];
            s2 += g1[4-k] * b0HH[u+k][m];
        }
        Y1c[u][m] = s1; Y2c[u][m] = s2;
    }
    __syncthreads();

    // ---- S8: level-0 row filter + store (verbatim) ----
    int u  = tid >> 3;
    int vb = (tid & 7) * 4;
    float o[4];
    #pragma unroll
    for (int j = 0; j < 4; ++j){
        int v = vb + j;
        float acc = 0.f;
        #pragma unroll
        for (int k = 0; k < 3; ++k) acc += g0[2-k] * Y1c[u][v+1+k];
        #pragma unroll
        for (int k = 0; k < 5; ++k) acc += g1[4-k] * Y2c[u][v+k];
        o[j] = acc;
    }
    store4(out, ((size_t)b*256 + R0 + u)*256 + C0 + vb, o[0], o[1], o[2], o[3]);
}

__global__ __launch_bounds__(256)
void kdtcwt(const void* yl, const void* yh0, const void* yh1, const void* yh2,
            const void* g0a, const void* g0o, const void* g1o, void* out)
{
    __shared__ __align__(16) char smem[FUSED_SMEM];
    // dtype detect from g0o word 0: bf16 packing puts bf16(0.70710678)=0x3F35 in the
    // high half; f32(0.35355339)=0x3EB504F3 has high half 0x3EB5. Block-uniform branch.
    unsigned w0 = *(const unsigned*)g0o;
    if ((w0 >> 16) == 0x3F35u)
        dtbody<bf16>(smem, (const bf16*)yl, (const bf16*)yh0, (const bf16*)yh1,
                     (const bf16*)yh2, (const bf16*)g0a, (const bf16*)g0o,
                     (const bf16*)g1o, (bf16*)out);
    else
        dtbody<float>(smem, (const float*)yl, (const float*)yh0, (const float*)yh1,
                      (const float*)yh2, (const float*)g0a, (const float*)g0o,
                      (const float*)g1o, (float*)out);
}

extern "C" void kernel_launch(void* const* d_in, const int* in_sizes, int n_in,
                              void* d_out, int out_size, void* d_ws, size_t ws_size,
                              hipStream_t stream) {
    const void* yl  = d_in[0];
    const void* yh0 = d_in[1];
    const void* yh1 = d_in[2];
    const void* yh2 = d_in[3];
    const void* g0o = d_in[4];
    const void* g1o = d_in[5];
    const void* g0a = d_in[6];
    // g0b/g1a/g1b (d_in[7..9]) are derived from g0a inside the kernel.

    kdtcwt<<<dim3(8, 8, 128), 256, 0, stream>>>(yl, yh0, yh1, yh2, g0a, g0o, g1o, d_out);
}